// Round 4
// baseline (607.524 us; speedup 1.0000x reference)
//
#include <hip/hip_runtime.h>

#define N_NODES 100000
#define N_EDGES 1600000
#define BN_EPS 1e-5f
#define NB_SCAN 98   // ceil(100000/1024)
#define TSTRIDE 48   // tmp row stride (40 padded to 3 aligned cache lines)

// broadcast lane k's value across the wave (readlane -> SGPR, free for VALU src)
// MUST be called only from wave-uniform (all-64-lanes-active) control flow.
__device__ __forceinline__ float bcast(float v, int k) {
    return __uint_as_float(__builtin_amdgcn_readlane(__float_as_uint(v), k));
}

// ===========================================================================
// CSR build: histogram -> 3-kernel exclusive scan -> fill
// ===========================================================================
__global__ __launch_bounds__(256) void histogram_kernel(
    const int* __restrict__ dst, int* __restrict__ deg)
{
    int e = blockIdx.x * 256 + threadIdx.x;
    if (e < N_EDGES) atomicAdd(&deg[dst[e]], 1);
}

__global__ __launch_bounds__(1024) void scan1_kernel(
    const int* __restrict__ deg, int* __restrict__ offs, int* __restrict__ bsum)
{
    __shared__ int tmp[1024];
    int gid = blockIdx.x * 1024 + threadIdx.x;
    int v = (gid < N_NODES) ? deg[gid] : 0;
    tmp[threadIdx.x] = v;
    __syncthreads();
    for (int off = 1; off < 1024; off <<= 1) {
        int t = (threadIdx.x >= off) ? tmp[threadIdx.x - off] : 0;
        __syncthreads();
        tmp[threadIdx.x] += t;
        __syncthreads();
    }
    if (gid < N_NODES) offs[gid] = tmp[threadIdx.x] - v;   // exclusive in-block
    if (threadIdx.x == 1023) bsum[blockIdx.x] = tmp[1023]; // block total
}

__global__ void scan2_kernel(int* __restrict__ bsum)
{
    __shared__ int tmp[128];
    int v = (threadIdx.x < NB_SCAN) ? bsum[threadIdx.x] : 0;
    tmp[threadIdx.x] = v;
    __syncthreads();
    for (int off = 1; off < 128; off <<= 1) {
        int t = (threadIdx.x >= off) ? tmp[threadIdx.x - off] : 0;
        __syncthreads();
        tmp[threadIdx.x] += t;
        __syncthreads();
    }
    if (threadIdx.x < NB_SCAN) bsum[threadIdx.x] = tmp[threadIdx.x] - v; // exclusive
}

__global__ __launch_bounds__(1024) void scan3_kernel(
    int* __restrict__ offs, const int* __restrict__ bsum, int* __restrict__ cursor)
{
    int gid = blockIdx.x * 1024 + threadIdx.x;
    if (gid < N_NODES) {
        int v = offs[gid] + bsum[blockIdx.x];
        offs[gid] = v;
        cursor[gid] = v;
    }
    if (gid == 0) offs[N_NODES] = N_EDGES;
}

__global__ __launch_bounds__(256) void fill_kernel(
    const int* __restrict__ src, const int* __restrict__ dst,
    int* __restrict__ cursor, int* __restrict__ nbr)
{
    int e = blockIdx.x * 256 + threadIdx.x;
    if (e < N_EDGES) {
        int p = atomicAdd(&cursor[dst[e]], 1);
        nbr[p] = src[e];
    }
}

// ===========================================================================
// dense1_lin: u = x @ W1l^T ; v = x @ W1r^T + b1  (written to hv buffer).
// Weight columns in VGPRs (128 regs); x row broadcast via readlane.
// 1 wave = 16 nodes sequentially, lane = output feature. Wave-uniform flow.
// ===========================================================================
__global__ __launch_bounds__(256) void dense1_lin_kernel(
    const float* __restrict__ x, const float* __restrict__ W1l,
    const float* __restrict__ W1r, const float* __restrict__ b1,
    float* __restrict__ u, float* __restrict__ hv)
{
    int f  = threadIdx.x & 63;
    int wv = threadIdx.x >> 6;
    float wl[64], wr[64];
#pragma unroll
    for (int k = 0; k < 64; ++k) {
        wl[k] = W1l[f * 64 + k];
        wr[k] = W1r[f * 64 + k];
    }
    float bias = b1[f];
    int node0 = blockIdx.x * 64;

    for (int nn = 0; nn < 16; ++nn) {
        int node = node0 + nn * 4 + wv;          // wave-uniform
        if (node < N_NODES) {
            float xv = x[(size_t)node * 64 + f];
            float ua = 0.f, va = bias;
#pragma unroll
            for (int k = 0; k < 64; ++k) {
                float xb = bcast(xv, k);
                ua += xb * wl[k];
                va += xb * wr[k];
            }
            u[(size_t)node * 64 + f]  = ua;
            hv[(size_t)node * 64 + f] = va;
        }
    }
}

// ===========================================================================
// gather1_bn: h = mean_{s in nbr(n)} u[s] + v  (in place over v in hv),
// plus BN partial sums. 16 nodes per wave -> only 1563 stat-atomics/address.
// 8-deep unrolled gather for MLP.
// ===========================================================================
__global__ __launch_bounds__(256) void gather1_bn_kernel(
    const float* __restrict__ u, const int* __restrict__ offs,
    const int* __restrict__ nbr, float* __restrict__ hv,
    float* __restrict__ sums, float* __restrict__ sumsq)
{
    int lane = threadIdx.x & 63;
    int wv   = threadIdx.x >> 6;
    int node0 = blockIdx.x * 64;
    float s1 = 0.f, s2 = 0.f;

    for (int nn = 0; nn < 16; ++nn) {
        int node = node0 + nn * 4 + wv;
        if (node < N_NODES) {
            int beg = offs[node], end = offs[node + 1];
            float a0=0.f,a1=0.f,a2=0.f,a3=0.f,a4=0.f,a5=0.f,a6=0.f,a7=0.f;
            int j = beg;
            for (; j + 7 < end; j += 8) {
                int s0=nbr[j],s1i=nbr[j+1],s2i=nbr[j+2],s3i=nbr[j+3];
                int s4=nbr[j+4],s5i=nbr[j+5],s6i=nbr[j+6],s7i=nbr[j+7];
                a0 += u[(size_t)s0  * 64 + lane];
                a1 += u[(size_t)s1i * 64 + lane];
                a2 += u[(size_t)s2i * 64 + lane];
                a3 += u[(size_t)s3i * 64 + lane];
                a4 += u[(size_t)s4  * 64 + lane];
                a5 += u[(size_t)s5i * 64 + lane];
                a6 += u[(size_t)s6i * 64 + lane];
                a7 += u[(size_t)s7i * 64 + lane];
            }
            for (; j < end; ++j) a0 += u[(size_t)nbr[j] * 64 + lane];
            float inv = 1.0f / (float)max(end - beg, 1);
            float hval = (((a0+a1)+(a2+a3)) + ((a4+a5)+(a6+a7))) * inv
                       + hv[(size_t)node * 64 + lane];
            hv[(size_t)node * 64 + lane] = hval;
            s1 += hval;
            s2 += hval * hval;
        }
    }

    __shared__ float red[256];
    red[threadIdx.x] = s1;
    __syncthreads();
    if (threadIdx.x < 64) {
        float t = red[threadIdx.x] + red[threadIdx.x + 64] +
                  red[threadIdx.x + 128] + red[threadIdx.x + 192];
        atomicAdd(&sums[threadIdx.x], t);
    }
    __syncthreads();
    red[threadIdx.x] = s2;
    __syncthreads();
    if (threadIdx.x < 64) {
        float t = red[threadIdx.x] + red[threadIdx.x + 64] +
                  red[threadIdx.x + 128] + red[threadIdx.x + 192];
        atomicAdd(&sumsq[threadIdx.x], t);
    }
}

// ===========================================================================
// BN finalize + apply
// ===========================================================================
__global__ void bn_finalize_kernel(
    const float* __restrict__ sums, const float* __restrict__ sumsq,
    const float* __restrict__ gamma, const float* __restrict__ beta,
    float* __restrict__ scale, float* __restrict__ shift)
{
    int f = threadIdx.x;
    if (f < 64) {
        float inv_n = 1.0f / (float)N_NODES;
        float mu  = sums[f] * inv_n;
        float var = sumsq[f] * inv_n - mu * mu;
        float rs  = rsqrtf(var + BN_EPS);
        float sc  = gamma[f] * rs;
        scale[f] = sc;
        shift[f] = beta[f] - mu * sc;
    }
}

__global__ __launch_bounds__(256) void bn_apply_kernel(
    float* __restrict__ h, const float* __restrict__ scale,
    const float* __restrict__ shift)
{
    __shared__ float sc[64], sh[64];
    if (threadIdx.x < 64) {
        sc[threadIdx.x] = scale[threadIdx.x];
        sh[threadIdx.x] = shift[threadIdx.x];
    }
    __syncthreads();
    int i = blockIdx.x * 256 + threadIdx.x;
    if (i < N_NODES * 16) {
        float4 v = ((float4*)h)[i];
        int f = (i & 15) * 4;
        v.x = fmaxf(v.x * sc[f + 0] + sh[f + 0], 0.f);
        v.y = fmaxf(v.y * sc[f + 1] + sh[f + 1], 0.f);
        v.z = fmaxf(v.z * sc[f + 2] + sh[f + 2], 0.f);
        v.w = fmaxf(v.w * sc[f + 3] + sh[f + 3], 0.f);
        ((float4*)h)[i] = v;
    }
}

// ===========================================================================
// dense2_lin: tmp = h @ W2l^T (stride-48 rows); out = h @ W2r^T + b2.
// Uniform readlane flow (clamped weight row for lanes >= 40); only stores
// are predicated.
// ===========================================================================
__global__ __launch_bounds__(256) void dense2_lin_kernel(
    const float* __restrict__ h, const float* __restrict__ W2l,
    const float* __restrict__ W2r, const float* __restrict__ b2,
    float* __restrict__ tmp, float* __restrict__ out)
{
    int f  = threadIdx.x & 63;
    int wv = threadIdx.x >> 6;
    int fc = (f < 40) ? f : 39;
    float wl[64], wr[64];
#pragma unroll
    for (int k = 0; k < 64; ++k) {
        wl[k] = W2l[fc * 64 + k];
        wr[k] = W2r[fc * 64 + k];
    }
    float bias = b2[fc];
    int node0 = blockIdx.x * 64;

    for (int nn = 0; nn < 16; ++nn) {
        int node = node0 + nn * 4 + wv;          // wave-uniform
        if (node < N_NODES) {
            float hvv = h[(size_t)node * 64 + f];
            float ta = 0.f, ra = bias;
#pragma unroll
            for (int k = 0; k < 64; ++k) {
                float hb = bcast(hvv, k);
                ta += hb * wl[k];
                ra += hb * wr[k];
            }
            if (f < 40) {
                tmp[(size_t)node * TSTRIDE + f] = ta;
                out[(size_t)node * 40 + f]      = ra;
            }
        }
    }
}

// ===========================================================================
// gather2: out[n] += mean_{s in nbr(n)} tmp[s]  (192B rows). No readlane;
// lanes >= 40 load clamped column (same cache lines), stores predicated.
// ===========================================================================
__global__ __launch_bounds__(256) void gather2_kernel(
    const float* __restrict__ tmp, const int* __restrict__ offs,
    const int* __restrict__ nbr, float* __restrict__ out)
{
    int lane = threadIdx.x & 63;
    int wv   = threadIdx.x >> 6;
    int cl   = (lane < TSTRIDE) ? lane : (TSTRIDE - 1);
    int node0 = blockIdx.x * 64;

    for (int nn = 0; nn < 16; ++nn) {
        int node = node0 + nn * 4 + wv;
        if (node < N_NODES) {
            int beg = offs[node], end = offs[node + 1];
            float a0=0.f,a1=0.f,a2=0.f,a3=0.f,a4=0.f,a5=0.f,a6=0.f,a7=0.f;
            int j = beg;
            for (; j + 7 < end; j += 8) {
                int s0=nbr[j],s1i=nbr[j+1],s2i=nbr[j+2],s3i=nbr[j+3];
                int s4=nbr[j+4],s5i=nbr[j+5],s6i=nbr[j+6],s7i=nbr[j+7];
                a0 += tmp[(size_t)s0  * TSTRIDE + cl];
                a1 += tmp[(size_t)s1i * TSTRIDE + cl];
                a2 += tmp[(size_t)s2i * TSTRIDE + cl];
                a3 += tmp[(size_t)s3i * TSTRIDE + cl];
                a4 += tmp[(size_t)s4  * TSTRIDE + cl];
                a5 += tmp[(size_t)s5i * TSTRIDE + cl];
                a6 += tmp[(size_t)s6i * TSTRIDE + cl];
                a7 += tmp[(size_t)s7i * TSTRIDE + cl];
            }
            for (; j < end; ++j) a0 += tmp[(size_t)nbr[j] * TSTRIDE + cl];
            float inv = 1.0f / (float)max(end - beg, 1);
            float g = (((a0+a1)+(a2+a3)) + ((a4+a5)+(a6+a7))) * inv;
            if (lane < 40) {
                size_t o = (size_t)node * 40 + lane;
                out[o] = out[o] + g;
            }
        }
    }
}

extern "C" void kernel_launch(void* const* d_in, const int* in_sizes, int n_in,
                              void* d_out, int out_size, void* d_ws, size_t ws_size,
                              hipStream_t stream)
{
    const float* x     = (const float*)d_in[0];
    const int*   ei    = (const int*)d_in[1];
    const float* W1l   = (const float*)d_in[2];
    const float* W1r   = (const float*)d_in[3];
    const float* b1    = (const float*)d_in[4];
    const float* gamma = (const float*)d_in[5];
    const float* beta  = (const float*)d_in[6];
    const float* W2l   = (const float*)d_in[7];
    const float* W2r   = (const float*)d_in[8];
    const float* b2    = (const float*)d_in[9];
    float* out = (float*)d_out;

    const int* src = ei;
    const int* dst = ei + N_EDGES;

    // workspace layout (58.8 MB total; R3 proved ws_size >= this):
    float* ws    = (float*)d_ws;
    float* buf1  = ws;                               // u [N*64], later tmp [N*48]
    float* buf2  = buf1 + (size_t)N_NODES * 64;      // v -> h (in place) [N*64]
    float* sums  = buf2 + (size_t)N_NODES * 64;      // 64
    float* sumsq = sums + 64;                        // 64
    float* scale = sumsq + 64;                       // 64
    float* shift = scale + 64;                       // 64
    int* deg    = (int*)(shift + 64);                // N
    int* offs   = deg + N_NODES;                     // N+1
    int* cursor = offs + N_NODES + 1;                // N
    int* bsum   = cursor + N_NODES;                  // 128
    int* nbr    = bsum + 128;                        // E

    dim3 blk(256);

    // ---- CSR build (reused by both layers) ----
    hipMemsetAsync(deg, 0, (size_t)N_NODES * sizeof(int), stream);
    hipMemsetAsync(sums, 0, 256 * sizeof(float), stream);
    histogram_kernel<<<(N_EDGES + 255) / 256, blk, 0, stream>>>(dst, deg);
    scan1_kernel<<<NB_SCAN, 1024, 0, stream>>>(deg, offs, bsum);
    scan2_kernel<<<1, 128, 0, stream>>>(bsum);
    scan3_kernel<<<NB_SCAN, 1024, 0, stream>>>(offs, bsum, cursor);
    fill_kernel<<<(N_EDGES + 255) / 256, blk, 0, stream>>>(src, dst, cursor, nbr);

    int gblocks = (N_NODES + 63) / 64;

    // ---- layer 1:  h = gather_mean(x @ W1l^T) + x @ W1r^T + b1 ----
    dense1_lin_kernel<<<gblocks, blk, 0, stream>>>(x, W1l, W1r, b1, buf1, buf2);
    gather1_bn_kernel<<<gblocks, blk, 0, stream>>>(buf1, offs, nbr, buf2, sums, sumsq);
    bn_finalize_kernel<<<1, 64, 0, stream>>>(sums, sumsq, gamma, beta, scale, shift);
    bn_apply_kernel<<<(N_NODES * 16 + 255) / 256, blk, 0, stream>>>(buf2, scale, shift);

    // ---- layer 2:  out = gather_mean(h @ W2l^T) + h @ W2r^T + b2 ----
    dense2_lin_kernel<<<gblocks, blk, 0, stream>>>(buf2, W2l, W2r, b2, buf1, out);
    gather2_kernel<<<gblocks, blk, 0, stream>>>(buf1, offs, nbr, out);
}

// Round 5
// 602.966 us; speedup vs baseline: 1.0076x; 1.0076x over previous
//
#include <hip/hip_runtime.h>

#define N_NODES 100000
#define N_EDGES 1600000
#define BN_EPS 1e-5f
#define NB_SCAN 98   // ceil(100000/1024)

// broadcast lane k's value (readlane). Wave-uniform control flow ONLY.
__device__ __forceinline__ float bcast(float v, int k) {
    return __uint_as_float(__builtin_amdgcn_readlane(__float_as_uint(v), k));
}
__device__ __forceinline__ float bf16lo(unsigned int w) {
    return __uint_as_float(w << 16);
}
__device__ __forceinline__ float bf16hi(unsigned int w) {
    return __uint_as_float(w & 0xFFFF0000u);
}
__device__ __forceinline__ unsigned short f2bf(float x) {   // round-nearest-even
    unsigned int u = __float_as_uint(x);
    return (unsigned short)((u + 0x7FFF + ((u >> 16) & 1)) >> 16);
}

// ===========================================================================
// CSR build: histogram -> 3-kernel exclusive scan -> fill
// ===========================================================================
__global__ __launch_bounds__(256) void histogram_kernel(
    const int* __restrict__ dst, int* __restrict__ deg)
{
    int e = blockIdx.x * 256 + threadIdx.x;
    if (e < N_EDGES) atomicAdd(&deg[dst[e]], 1);
}

__global__ __launch_bounds__(1024) void scan1_kernel(
    const int* __restrict__ deg, int* __restrict__ offs, int* __restrict__ bsum)
{
    __shared__ int tmp[1024];
    int gid = blockIdx.x * 1024 + threadIdx.x;
    int v = (gid < N_NODES) ? deg[gid] : 0;
    tmp[threadIdx.x] = v;
    __syncthreads();
    for (int off = 1; off < 1024; off <<= 1) {
        int t = (threadIdx.x >= off) ? tmp[threadIdx.x - off] : 0;
        __syncthreads();
        tmp[threadIdx.x] += t;
        __syncthreads();
    }
    if (gid < N_NODES) offs[gid] = tmp[threadIdx.x] - v;
    if (threadIdx.x == 1023) bsum[blockIdx.x] = tmp[1023];
}

__global__ void scan2_kernel(int* __restrict__ bsum)
{
    __shared__ int tmp[128];
    int v = (threadIdx.x < NB_SCAN) ? bsum[threadIdx.x] : 0;
    tmp[threadIdx.x] = v;
    __syncthreads();
    for (int off = 1; off < 128; off <<= 1) {
        int t = (threadIdx.x >= off) ? tmp[threadIdx.x - off] : 0;
        __syncthreads();
        tmp[threadIdx.x] += t;
        __syncthreads();
    }
    if (threadIdx.x < NB_SCAN) bsum[threadIdx.x] = tmp[threadIdx.x] - v;
}

__global__ __launch_bounds__(1024) void scan3_kernel(
    int* __restrict__ offs, const int* __restrict__ bsum, int* __restrict__ cursor)
{
    int gid = blockIdx.x * 1024 + threadIdx.x;
    if (gid < N_NODES) {
        int v = offs[gid] + bsum[blockIdx.x];
        offs[gid] = v;
        cursor[gid] = v;
    }
    if (gid == 0) offs[N_NODES] = N_EDGES;
}

__global__ __launch_bounds__(256) void fill_kernel(
    const int* __restrict__ src, const int* __restrict__ dst,
    int* __restrict__ cursor, int* __restrict__ nbr)
{
    int e = blockIdx.x * 256 + threadIdx.x;
    if (e < N_EDGES) {
        int p = atomicAdd(&cursor[dst[e]], 1);
        nbr[p] = src[e];
    }
}

// ===========================================================================
// dense1_lin: u(bf16) = x @ W1l^T ; hv(f32) = x @ W1r^T + b1.
// Weights staged coalesced global->LDS (transposed, pad 65) then one-time
// conflict-free ds_reads into per-lane register arrays.
// ===========================================================================
__global__ __launch_bounds__(256) void dense1_lin_kernel(
    const float* __restrict__ x, const float* __restrict__ W1l,
    const float* __restrict__ W1r, const float* __restrict__ b1,
    unsigned short* __restrict__ u, float* __restrict__ hv)
{
    __shared__ float wlT[64 * 65];
    __shared__ float wrT[64 * 65];
    for (int idx = threadIdx.x; idx < 4096; idx += 256) {
        int f = idx >> 6, k = idx & 63;
        wlT[k * 65 + f] = W1l[idx];          // (k+f)%32 banks: conflict-free
        wrT[k * 65 + f] = W1r[idx];
    }
    __syncthreads();

    int f  = threadIdx.x & 63;
    int wv = threadIdx.x >> 6;
    float wl[64], wr[64];
#pragma unroll
    for (int k = 0; k < 64; ++k) {
        wl[k] = wlT[k * 65 + f];
        wr[k] = wrT[k * 65 + f];
    }
    float bias = b1[f];
    int node0 = blockIdx.x * 64;

    for (int nn = 0; nn < 16; ++nn) {
        int node = node0 + nn * 4 + wv;          // wave-uniform
        if (node < N_NODES) {
            float xv = x[(size_t)node * 64 + f];
            float ua = 0.f, va = bias;
#pragma unroll
            for (int k = 0; k < 64; ++k) {
                float xb = bcast(xv, k);
                ua += xb * wl[k];
                va += xb * wr[k];
            }
            u[(size_t)node * 64 + f]  = f2bf(ua);
            hv[(size_t)node * 64 + f] = va;
        }
    }
}

// ===========================================================================
// gather1_bn: h = mean(u[nbr]) + v, in place over hv; BN partial sums.
// u is bf16: lane covers 2 features; half-wave 0 = edge j, half 1 = edge j+1.
// 8 pair-steps unrolled -> 16 edges in flight per node.
// ===========================================================================
__global__ __launch_bounds__(256) void gather1_bn_kernel(
    const unsigned int* __restrict__ u32, const int* __restrict__ offs,
    const int* __restrict__ nbr, float* __restrict__ hv,
    float* __restrict__ sums, float* __restrict__ sumsq)
{
    int lane = threadIdx.x & 63;
    int m    = lane & 31;
    int half = lane >> 5;
    int wv   = threadIdx.x >> 6;
    int node0 = blockIdx.x * 64;
    float s1_0 = 0.f, s1_1 = 0.f, s2_0 = 0.f, s2_1 = 0.f;

    for (int nn = 0; nn < 16; ++nn) {
        int node = node0 + nn * 4 + wv;
        if (node < N_NODES) {
            int beg = offs[node], end = offs[node + 1];
            float p0=0,p1=0,p2=0,p3=0,p4=0,p5=0,p6=0,p7=0;
            float q0=0,q1=0,q2=0,q3=0,q4=0,q5=0,q6=0,q7=0;
            int j = beg;
            for (; j + 16 <= end; j += 16) {
                unsigned int w0 = u32[(size_t)nbr[j +  0 + half] * 32 + m];
                unsigned int w1 = u32[(size_t)nbr[j +  2 + half] * 32 + m];
                unsigned int w2 = u32[(size_t)nbr[j +  4 + half] * 32 + m];
                unsigned int w3 = u32[(size_t)nbr[j +  6 + half] * 32 + m];
                unsigned int w4 = u32[(size_t)nbr[j +  8 + half] * 32 + m];
                unsigned int w5 = u32[(size_t)nbr[j + 10 + half] * 32 + m];
                unsigned int w6 = u32[(size_t)nbr[j + 12 + half] * 32 + m];
                unsigned int w7 = u32[(size_t)nbr[j + 14 + half] * 32 + m];
                p0 += bf16lo(w0); q0 += bf16hi(w0);
                p1 += bf16lo(w1); q1 += bf16hi(w1);
                p2 += bf16lo(w2); q2 += bf16hi(w2);
                p3 += bf16lo(w3); q3 += bf16hi(w3);
                p4 += bf16lo(w4); q4 += bf16hi(w4);
                p5 += bf16lo(w5); q5 += bf16hi(w5);
                p6 += bf16lo(w6); q6 += bf16hi(w6);
                p7 += bf16lo(w7); q7 += bf16hi(w7);
            }
            for (; j + 2 <= end; j += 2) {
                unsigned int w = u32[(size_t)nbr[j + half] * 32 + m];
                p0 += bf16lo(w); q0 += bf16hi(w);
            }
            if (j + half < end) {   // odd leftover: half 0 only
                unsigned int w = u32[(size_t)nbr[j] * 32 + m];
                p0 += bf16lo(w); q0 += bf16hi(w);
            }
            float P = ((p0+p1)+(p2+p3)) + ((p4+p5)+(p6+p7));
            float Q = ((q0+q1)+(q2+q3)) + ((q4+q5)+(q6+q7));
            P += __shfl_xor(P, 32);   // combine halves (all lanes active)
            Q += __shfl_xor(Q, 32);
            if (half == 0) {
                float inv = 1.0f / (float)max(end - beg, 1);
                float2 v = ((const float2*)hv)[(size_t)node * 32 + m];
                float h0 = P * inv + v.x;
                float h1 = Q * inv + v.y;
                ((float2*)hv)[(size_t)node * 32 + m] = make_float2(h0, h1);
                s1_0 += h0; s1_1 += h1;
                s2_0 += h0 * h0; s2_1 += h1 * h1;
            }
        }
    }

    __shared__ float2 redA[256];
    __shared__ float2 redB[256];
    redA[threadIdx.x] = make_float2(s1_0, s1_1);
    redB[threadIdx.x] = make_float2(s2_0, s2_1);
    __syncthreads();
    if (threadIdx.x < 32) {
        int mm = threadIdx.x;
        float a0=0,a1=0,b0=0,b1=0;
        for (int w = 0; w < 4; ++w) {
            float2 A = redA[w * 64 + mm]; a0 += A.x; a1 += A.y;
            float2 B = redB[w * 64 + mm]; b0 += B.x; b1 += B.y;
        }
        atomicAdd(&sums[2 * mm], a0);  atomicAdd(&sums[2 * mm + 1], a1);
        atomicAdd(&sumsq[2 * mm], b0); atomicAdd(&sumsq[2 * mm + 1], b1);
    }
}

// ===========================================================================
// BN finalize
// ===========================================================================
__global__ void bn_finalize_kernel(
    const float* __restrict__ sums, const float* __restrict__ sumsq,
    const float* __restrict__ gamma, const float* __restrict__ beta,
    float* __restrict__ scale, float* __restrict__ shift)
{
    int f = threadIdx.x;
    if (f < 64) {
        float inv_n = 1.0f / (float)N_NODES;
        float mu  = sums[f] * inv_n;
        float var = sumsq[f] * inv_n - mu * mu;
        float rs  = rsqrtf(var + BN_EPS);
        float sc  = gamma[f] * rs;
        scale[f] = sc;
        shift[f] = beta[f] - mu * sc;
    }
}

// ===========================================================================
// dense2_bn: BN+ReLU fused per-lane, then tmp(bf16,packed 40) = hn @ W2l^T,
// out = hn @ W2r^T + b2. Uniform readlane flow; stores predicated.
// ===========================================================================
__global__ __launch_bounds__(256) void dense2_bn_kernel(
    const float* __restrict__ h, const float* __restrict__ scale,
    const float* __restrict__ shift, const float* __restrict__ W2l,
    const float* __restrict__ W2r, const float* __restrict__ b2,
    unsigned short* __restrict__ tmp, float* __restrict__ out)
{
    __shared__ float wlT[64 * 65];
    __shared__ float wrT[64 * 65];
    for (int idx = threadIdx.x; idx < 2560; idx += 256) {
        int f = idx >> 6, k = idx & 63;      // f < 40
        wlT[k * 65 + f] = W2l[idx];
        wrT[k * 65 + f] = W2r[idx];
    }
    __syncthreads();

    int f  = threadIdx.x & 63;
    int wv = threadIdx.x >> 6;
    int fc = (f < 40) ? f : 39;
    float wl[64], wr[64];
#pragma unroll
    for (int k = 0; k < 64; ++k) {
        wl[k] = wlT[k * 65 + fc];
        wr[k] = wrT[k * 65 + fc];
    }
    float bias = b2[fc];
    float sc = scale[f], sh = shift[f];      // real f: all 64 lanes feed bcast
    int node0 = blockIdx.x * 64;

    for (int nn = 0; nn < 16; ++nn) {
        int node = node0 + nn * 4 + wv;          // wave-uniform
        if (node < N_NODES) {
            float hvv = h[(size_t)node * 64 + f];
            float hn  = fmaxf(hvv * sc + sh, 0.f);   // BN + ReLU fused
            float ta = 0.f, ra = bias;
#pragma unroll
            for (int k = 0; k < 64; ++k) {
                float hb = bcast(hn, k);
                ta += hb * wl[k];
                ra += hb * wr[k];
            }
            if (f < 40) {
                tmp[(size_t)node * 40 + f] = f2bf(ta);
                out[(size_t)node * 40 + f] = ra;
            }
        }
    }
}

// ===========================================================================
// gather2: out += mean(tmp[nbr]); tmp bf16 packed 40 (80B rows, 2 lines).
// Lanes m<20 active per half; 2 edges per load step, 8-deep unroll.
// ===========================================================================
__global__ __launch_bounds__(256) void gather2_kernel(
    const unsigned int* __restrict__ t32, const int* __restrict__ offs,
    const int* __restrict__ nbr, float* __restrict__ out)
{
    int lane = threadIdx.x & 63;
    int m    = lane & 31;
    int half = lane >> 5;
    bool act = (m < 20);
    int wv   = threadIdx.x >> 6;
    int node0 = blockIdx.x * 64;

    for (int nn = 0; nn < 16; ++nn) {
        int node = node0 + nn * 4 + wv;
        if (node < N_NODES) {
            int beg = offs[node], end = offs[node + 1];
            float p0=0,p1=0,p2=0,p3=0,p4=0,p5=0,p6=0,p7=0;
            float q0=0,q1=0,q2=0,q3=0,q4=0,q5=0,q6=0,q7=0;
            int j = beg;
            for (; j + 16 <= end; j += 16) {
                if (act) {
                    unsigned int w0 = t32[(size_t)nbr[j +  0 + half] * 20 + m];
                    unsigned int w1 = t32[(size_t)nbr[j +  2 + half] * 20 + m];
                    unsigned int w2 = t32[(size_t)nbr[j +  4 + half] * 20 + m];
                    unsigned int w3 = t32[(size_t)nbr[j +  6 + half] * 20 + m];
                    unsigned int w4 = t32[(size_t)nbr[j +  8 + half] * 20 + m];
                    unsigned int w5 = t32[(size_t)nbr[j + 10 + half] * 20 + m];
                    unsigned int w6 = t32[(size_t)nbr[j + 12 + half] * 20 + m];
                    unsigned int w7 = t32[(size_t)nbr[j + 14 + half] * 20 + m];
                    p0 += bf16lo(w0); q0 += bf16hi(w0);
                    p1 += bf16lo(w1); q1 += bf16hi(w1);
                    p2 += bf16lo(w2); q2 += bf16hi(w2);
                    p3 += bf16lo(w3); q3 += bf16hi(w3);
                    p4 += bf16lo(w4); q4 += bf16hi(w4);
                    p5 += bf16lo(w5); q5 += bf16hi(w5);
                    p6 += bf16lo(w6); q6 += bf16hi(w6);
                    p7 += bf16lo(w7); q7 += bf16hi(w7);
                }
            }
            for (; j + 2 <= end; j += 2) {
                if (act) {
                    unsigned int w = t32[(size_t)nbr[j + half] * 20 + m];
                    p0 += bf16lo(w); q0 += bf16hi(w);
                }
            }
            if (act && (j + half < end)) {
                unsigned int w = t32[(size_t)nbr[j] * 20 + m];
                p0 += bf16lo(w); q0 += bf16hi(w);
            }
            float P = ((p0+p1)+(p2+p3)) + ((p4+p5)+(p6+p7));
            float Q = ((q0+q1)+(q2+q3)) + ((q4+q5)+(q6+q7));
            P += __shfl_xor(P, 32);
            Q += __shfl_xor(Q, 32);
            if (half == 0 && act) {
                float inv = 1.0f / (float)max(end - beg, 1);
                float2 o = ((float2*)out)[(size_t)node * 20 + m];
                o.x += P * inv;
                o.y += Q * inv;
                ((float2*)out)[(size_t)node * 20 + m] = o;
            }
        }
    }
}

extern "C" void kernel_launch(void* const* d_in, const int* in_sizes, int n_in,
                              void* d_out, int out_size, void* d_ws, size_t ws_size,
                              hipStream_t stream)
{
    const float* x     = (const float*)d_in[0];
    const int*   ei    = (const int*)d_in[1];
    const float* W1l   = (const float*)d_in[2];
    const float* W1r   = (const float*)d_in[3];
    const float* b1    = (const float*)d_in[4];
    const float* gamma = (const float*)d_in[5];
    const float* beta  = (const float*)d_in[6];
    const float* W2l   = (const float*)d_in[7];
    const float* W2r   = (const float*)d_in[8];
    const float* b2    = (const float*)d_in[9];
    float* out = (float*)d_out;

    const int* src = ei;
    const int* dst = ei + N_EDGES;

    // workspace layout (~54 MB; 58.8 MB proven available in R3):
    float* ws    = (float*)d_ws;
    float* hv    = ws;                               // f32 [N*64]
    float* sums  = hv + (size_t)N_NODES * 64;        // 64
    float* sumsq = sums + 64;
    float* scale = sumsq + 64;
    float* shift = scale + 64;
    unsigned short* u = (unsigned short*)(shift + 64);   // bf16 [N*64]
    unsigned short* tmpb = u;                        // bf16 [N*40], reuses u
    int* deg    = (int*)(u + (size_t)N_NODES * 64);  // N
    int* offs   = deg + N_NODES;                     // N+1
    int* cursor = offs + N_NODES + 1;                // N
    int* bsum   = cursor + N_NODES;                  // 128
    int* nbr    = bsum + 128;                        // E

    dim3 blk(256);

    // ---- CSR build ----
    hipMemsetAsync(deg, 0, (size_t)N_NODES * sizeof(int), stream);
    hipMemsetAsync(sums, 0, 256 * sizeof(float), stream);
    histogram_kernel<<<(N_EDGES + 255) / 256, blk, 0, stream>>>(dst, deg);
    scan1_kernel<<<NB_SCAN, 1024, 0, stream>>>(deg, offs, bsum);
    scan2_kernel<<<1, 128, 0, stream>>>(bsum);
    scan3_kernel<<<NB_SCAN, 1024, 0, stream>>>(offs, bsum, cursor);
    fill_kernel<<<(N_EDGES + 255) / 256, blk, 0, stream>>>(src, dst, cursor, nbr);

    int gblocks = (N_NODES + 63) / 64;

    // ---- layer 1 ----
    dense1_lin_kernel<<<gblocks, blk, 0, stream>>>(x, W1l, W1r, b1, u, hv);
    gather1_bn_kernel<<<gblocks, blk, 0, stream>>>(
        (const unsigned int*)u, offs, nbr, hv, sums, sumsq);
    bn_finalize_kernel<<<1, 64, 0, stream>>>(sums, sumsq, gamma, beta, scale, shift);

    // ---- layer 2 (BN+ReLU fused into dense2) ----
    dense2_bn_kernel<<<gblocks, blk, 0, stream>>>(
        hv, scale, shift, W2l, W2r, b2, tmpb, out);
    gather2_kernel<<<gblocks, blk, 0, stream>>>(
        (const unsigned int*)tmpb, offs, nbr, out);
}